// Round 7
// baseline (78.131 us; speedup 1.0000x reference)
//
#include <hip/hip_runtime.h>

// MeanAggregator: 4 fused gather outputs.
//   out0 = mean_k features[neigh_idx[b,k]]          [B, D]
//   out1 = mean_k features[perm[neigh_idx[b,k]]]    [B, D]
//   out2 = features[nodes[b]]                       [B, D]
//   out3 = features[perm[nodes[b]]]                 [B, D]
// B=16384, K=10, D=256, features [100000, 256] f32.
//
// R7: padded-bucket phasing = R5's L2 locality + R4's MLP.
// R6 post-mortem: variable-trip bucket loops serialize (load;wait;add per
// iter -> depth-1 MLP -> latency-bound, 94us model ~= 102us measured).
// Fix: pad each phase bucket to a multiple of 4 by duplicating the last
// valid entry (duplicate loads are L2-hot; their contribution is
// zero-selected before the add), then walk buckets in fixed 4-wide
// unrolled steps -> 4 independent loads in flight per step.
// Keeps XCD-affine D-slicing (slice=blockIdx%8) + NT stores.

typedef float f32x4 __attribute__((ext_vector_type(4)));

constexpr int BATCH    = 16384;
constexpr int K_SAMPLE = 10;
constexpr int D_FEAT   = 256;
constexpr int N_NODES  = 100000;
constexpr int SLICES   = 8;                 // 32 dims (128 B) per slice
constexpr int SLICE_D  = D_FEAT / SLICES;   // 32 floats
constexpr int CHUNK    = 32;                // batch rows per block
constexpr int THREADS  = 256;               // 8 threads/row x 32 rows
constexpr int PHASES   = 4;
constexpr int RANGE    = N_NODES / PHASES;  // 25000 rows -> 3.2 MB/XCD window
constexpr int LSTRIDE  = 25;                // padded list stride (coprime w/ 32)

__global__ __launch_bounds__(THREADS)
void mean_agg_kernel(const float* __restrict__ features,
                     const int*   __restrict__ neigh_idx,
                     const int*   __restrict__ nodes,
                     const int*   __restrict__ perm,
                     float*       __restrict__ out)
{
    const int slice = blockIdx.x & (SLICES - 1);   // -> XCD id (round-robin)
    const int chunk = blockIdx.x >> 3;

    const int t     = threadIdx.x;
    const int g     = t >> 3;                      // row-in-chunk 0..31
    const int lane8 = t & 7;                       // float4 column in slice

    const int b = chunk * CHUNK + g;
    const int d = slice * SLICE_D + lane8 * 4;

    __shared__ int s_tmp [2][CHUNK * K_SAMPLE];    // raw idx / perm[idx]
    __shared__ int s_list[2][CHUNK][LSTRIDE];      // phase-sorted, 4-padded
    __shared__ int s_base[2][CHUNK][PHASES];       // padded bucket base
    __shared__ int s_cnt [2][CHUNK][PHASES];       // real bucket count
    __shared__ int s_n [CHUNK];
    __shared__ int s_pn[CHUNK];

    // ---- stage indices + perm lookups ----
    for (int i = t; i < CHUNK * K_SAMPLE; i += THREADS) {
        const int idx = neigh_idx[chunk * CHUNK * K_SAMPLE + i];
        s_tmp[0][i] = idx;
        s_tmp[1][i] = perm[idx];
    }
    if (t < CHUNK) {
        const int n = nodes[chunk * CHUNK + t];
        s_n [t] = n;
        s_pn[t] = perm[n];
    }
    __syncthreads();

    // ---- skip (self) gathers: unphased, in flight during the sort ----
    const f32x4 o2 = *reinterpret_cast<const f32x4*>(
        &features[(size_t)s_n [g] * D_FEAT + d]);
    const f32x4 o3 = *reinterpret_cast<const f32x4*>(
        &features[(size_t)s_pn[g] * D_FEAT + d]);

    // ---- counting sort into 4-padded phase buckets: 64 workers ----
    if (t < 2 * CHUNK) {
        const int tb = t >> 5;                     // table 0..1
        const int r  = t & (CHUNK - 1);            // row 0..31
        int cnt[PHASES] = {0, 0, 0, 0};
        int ph[K_SAMPLE], vals[K_SAMPLE];
        #pragma unroll
        for (int k = 0; k < K_SAMPLE; ++k) {
            const int idx = s_tmp[tb][r * K_SAMPLE + k];
            vals[k] = idx;
            const int p = idx / RANGE;             // const-div -> mulhi+shift
            ph[k] = p;
            ++cnt[p];
        }
        int pb[PHASES];
        int off = 0;
        #pragma unroll
        for (int p = 0; p < PHASES; ++p) {
            pb[p] = off;
            s_base[tb][r][p] = off;
            s_cnt [tb][r][p] = cnt[p];
            off += (cnt[p] + 3) & ~3;              // pad to multiple of 4
        }
        int pos[PHASES] = {pb[0], pb[1], pb[2], pb[3]};
        #pragma unroll
        for (int k = 0; k < K_SAMPLE; ++k)
            s_list[tb][r][pos[ph[k]]++] = vals[k];
        // pad each non-empty bucket by duplicating its last valid entry
        #pragma unroll
        for (int p = 0; p < PHASES; ++p) {
            const int c = cnt[p];
            if (c) {
                const int last = s_list[tb][r][pos[p] - 1];
                const int end  = pb[p] + ((c + 3) & ~3);
                for (int q = pos[p]; q < end; ++q)
                    s_list[tb][r][q] = last;
            }
        }
    }
    __syncthreads();

    // ---- phase sweep: fixed 4-wide steps, 4 independent loads each ----
    f32x4 acc  = {0.f, 0.f, 0.f, 0.f};
    f32x4 accs = {0.f, 0.f, 0.f, 0.f};
    const f32x4 zero = {0.f, 0.f, 0.f, 0.f};

    for (int p = 0; p < PHASES; ++p) {
        #pragma unroll
        for (int tb = 0; tb < 2; ++tb) {
            const int base = s_base[tb][g][p];
            const int c    = s_cnt [tb][g][p];
            f32x4 local = {0.f, 0.f, 0.f, 0.f};
            for (int j = 0; j < c; j += 4) {       // <= 3 iterations
                const int i0 = s_list[tb][g][base + j + 0];
                const int i1 = s_list[tb][g][base + j + 1];
                const int i2 = s_list[tb][g][base + j + 2];
                const int i3 = s_list[tb][g][base + j + 3];
                const f32x4 f0 = *reinterpret_cast<const f32x4*>(
                    &features[(size_t)i0 * D_FEAT + d]);
                const f32x4 f1 = *reinterpret_cast<const f32x4*>(
                    &features[(size_t)i1 * D_FEAT + d]);
                const f32x4 f2 = *reinterpret_cast<const f32x4*>(
                    &features[(size_t)i2 * D_FEAT + d]);
                const f32x4 f3 = *reinterpret_cast<const f32x4*>(
                    &features[(size_t)i3 * D_FEAT + d]);
                local += f0;                       // j+0 < c guaranteed
                local += (j + 1 < c) ? f1 : zero;  // pads select to zero
                local += (j + 2 < c) ? f2 : zero;
                local += (j + 3 < c) ? f3 : zero;
            }
            if (tb == 0) acc += local; else accs += local;
        }
        __syncthreads();   // keep the block's waves phase-aligned
    }

    const float inv = 1.0f / (float)K_SAMPLE;
    const f32x4 o0 = acc  * inv;
    const f32x4 o1 = accs * inv;

    // ---- stores: outputs concatenated flat in return order ----
    const size_t row = (size_t)b * D_FEAT + d;
    const size_t sec = (size_t)BATCH * D_FEAT;
    __builtin_nontemporal_store(o0, reinterpret_cast<f32x4*>(&out[row]          ));
    __builtin_nontemporal_store(o1, reinterpret_cast<f32x4*>(&out[row +     sec]));
    __builtin_nontemporal_store(o2, reinterpret_cast<f32x4*>(&out[row + 2 * sec]));
    __builtin_nontemporal_store(o3, reinterpret_cast<f32x4*>(&out[row + 3 * sec]));
}

extern "C" void kernel_launch(void* const* d_in, const int* in_sizes, int n_in,
                              void* d_out, int out_size, void* d_ws, size_t ws_size,
                              hipStream_t stream) {
    const float* features  = (const float*)d_in[0];
    const int*   neigh_idx = (const int*)  d_in[1];
    const int*   nodes     = (const int*)  d_in[2];
    const int*   perm      = (const int*)  d_in[3];
    float*       out       = (float*)d_out;

    const int grid = (BATCH / CHUNK) * SLICES;     // 512 chunks x 8 slices = 4096
    mean_agg_kernel<<<grid, THREADS, 0, stream>>>(features, neigh_idx, nodes, perm, out);
}

// Round 8
// 71.992 us; speedup vs baseline: 1.0853x; 1.0853x over previous
//
#include <hip/hip_runtime.h>

// MeanAggregator: 4 fused gather outputs.
//   out0 = mean_k features[neigh_idx[b,k]]          [B, D]
//   out1 = mean_k features[perm[neigh_idx[b,k]]]    [B, D]
//   out2 = features[nodes[b]]                       [B, D]
//   out3 = features[perm[nodes[b]]]                 [B, D]
// B=16384, K=10, D=256, features [100000, 256] f32.
//
// R8: minimal 2-phase predicated windowing on top of R4.
// Phasing failure modes so far: R5 = 4x issue count (P=4 re-scan),
// R6 = depth-1 MLP (variable-trip bucket loops), R7 = occupancy +
// cross-block phase misalignment (sort machinery). Fix all three:
//   - P=2 re-scan: only 2x issues, no sort, no divergent loops
//   - indices in REGISTERS (20 VGPRs), scanned twice, fully unrolled
//     -> ~20 exec-masked loads in flight per phase
//   - generation-rotated window order ((blockIdx>>11)&1): the two
//     co-resident launch generations sweep windows in opposite order
//     so concurrently-running blocks share the same 6.4 MB/XCD window
// Keeps R4's XCD-affine D-slicing (slice=blockIdx%8) + NT stores.

typedef float f32x4 __attribute__((ext_vector_type(4)));

constexpr int BATCH    = 16384;
constexpr int K_SAMPLE = 10;
constexpr int D_FEAT   = 256;
constexpr int N_NODES  = 100000;
constexpr int SLICES   = 8;                 // 32 dims (128 B) per slice
constexpr int SLICE_D  = D_FEAT / SLICES;   // 32 floats
constexpr int CHUNK    = 32;                // batch rows per block
constexpr int THREADS  = 256;               // 8 threads/row x 32 rows
constexpr int PHASES   = 2;
constexpr int RANGE    = N_NODES / PHASES;  // 50000 rows -> 6.4 MB/XCD window

__global__ __launch_bounds__(THREADS)
void mean_agg_kernel(const float* __restrict__ features,
                     const int*   __restrict__ neigh_idx,
                     const int*   __restrict__ nodes,
                     const int*   __restrict__ perm,
                     float*       __restrict__ out)
{
    const int slice = blockIdx.x & (SLICES - 1);   // -> XCD id (round-robin)
    const int chunk = blockIdx.x >> 3;
    const int gen   = (blockIdx.x >> 11) & 1;      // co-resident generation

    const int t     = threadIdx.x;
    const int g     = t >> 3;                      // row-in-chunk 0..31
    const int lane8 = t & 7;                       // float4 column in slice

    const int b = chunk * CHUNK + g;
    const int d = slice * SLICE_D + lane8 * 4;

    // ---- skip (self) gathers first: 3-deep chain overlaps everything ----
    const int n  = nodes[b];
    const int pn = perm[n];
    const f32x4 o2 = *reinterpret_cast<const f32x4*>(
        &features[(size_t)n  * D_FEAT + d]);
    const f32x4 o3 = *reinterpret_cast<const f32x4*>(
        &features[(size_t)pn * D_FEAT + d]);

    // ---- stage all indices in registers (loaded once, scanned twice) ----
    int idx[K_SAMPLE], pidx[K_SAMPLE];
    #pragma unroll
    for (int k = 0; k < K_SAMPLE; ++k) {
        idx[k]  = neigh_idx[b * K_SAMPLE + k];
        pidx[k] = perm[idx[k]];
    }

    // ---- 2-phase window sweep, fully unrolled, predicated gathers ----
    f32x4 acc  = {0.f, 0.f, 0.f, 0.f};
    f32x4 accs = {0.f, 0.f, 0.f, 0.f};

    #pragma unroll
    for (int p = 0; p < PHASES; ++p) {
        const int w  = p ^ gen;                    // rotated window order
        const int lo = w * RANGE;

        #pragma unroll
        for (int k = 0; k < K_SAMPLE; ++k) {
            if ((unsigned)(idx[k] - lo) < (unsigned)RANGE)
                acc += *reinterpret_cast<const f32x4*>(
                    &features[(size_t)idx[k] * D_FEAT + d]);
            if ((unsigned)(pidx[k] - lo) < (unsigned)RANGE)
                accs += *reinterpret_cast<const f32x4*>(
                    &features[(size_t)pidx[k] * D_FEAT + d]);
        }
        __syncthreads();   // keep the block's waves window-aligned
    }

    const float inv = 1.0f / (float)K_SAMPLE;
    const f32x4 o0 = acc  * inv;
    const f32x4 o1 = accs * inv;

    // ---- stores: outputs concatenated flat in return order ----
    const size_t row = (size_t)b * D_FEAT + d;
    const size_t sec = (size_t)BATCH * D_FEAT;
    __builtin_nontemporal_store(o0, reinterpret_cast<f32x4*>(&out[row]          ));
    __builtin_nontemporal_store(o1, reinterpret_cast<f32x4*>(&out[row +     sec]));
    __builtin_nontemporal_store(o2, reinterpret_cast<f32x4*>(&out[row + 2 * sec]));
    __builtin_nontemporal_store(o3, reinterpret_cast<f32x4*>(&out[row + 3 * sec]));
}

extern "C" void kernel_launch(void* const* d_in, const int* in_sizes, int n_in,
                              void* d_out, int out_size, void* d_ws, size_t ws_size,
                              hipStream_t stream) {
    const float* features  = (const float*)d_in[0];
    const int*   neigh_idx = (const int*)  d_in[1];
    const int*   nodes     = (const int*)  d_in[2];
    const int*   perm      = (const int*)  d_in[3];
    float*       out       = (float*)d_out;

    const int grid = (BATCH / CHUNK) * SLICES;     // 512 chunks x 8 slices = 4096
    mean_agg_kernel<<<grid, THREADS, 0, stream>>>(features, neigh_idx, nodes, perm, out);
}

// Round 9
// 59.419 us; speedup vs baseline: 1.3149x; 1.2116x over previous
//
#include <hip/hip_runtime.h>

// MeanAggregator: 4 fused gather outputs.
//   out0 = mean_k features[neigh_idx[b,k]]          [B, D]
//   out1 = mean_k features[perm[neigh_idx[b,k]]]    [B, D]
//   out2 = features[nodes[b]]                       [B, D]
//   out3 = features[perm[nodes[b]]]                 [B, D]
// B=16384, K=10, D=256, features [100000, 256] f32.
//
// FINAL (revert to R4, the best variant at 59.8 us):
// XCD-affine D-slicing. Kernel is bound by L2-miss/fabric traffic
// (~344 MB @ ~5.75 TB/s ~= 91% of the 6.29 TB/s measured ceiling).
// Split D into 8 slices of 32 dims; slice = blockIdx%8 -> round-robin
// dispatch pins slice s to XCD s, so each XCD's L2 only sees its
// 12.8 MB sub-table (~31% hit on re-reads) instead of the whole 102 MB
// (~4% hit). Gathers are 8 threads x float4 = 128 B per slice.
// Phasing variants (R5-R8: P=4 re-scan, bucketed sort, padded buckets,
// P=2 register re-scan) ALL regressed: each cut HBM fetch but paid more
// in VMEM issue count / MLP / occupancy than the saved fabric bytes.

typedef float f32x4 __attribute__((ext_vector_type(4)));

constexpr int BATCH    = 16384;
constexpr int K_SAMPLE = 10;
constexpr int D_FEAT   = 256;
constexpr int SLICES   = 8;          // 32 dims (128 B) per slice
constexpr int SLICE_D  = D_FEAT / SLICES;           // 32 floats
constexpr int CHUNK    = 32;         // batch rows per block
constexpr int THREADS  = 256;        // 8 threads per row-slice x 32 rows

__global__ __launch_bounds__(THREADS)
void mean_agg_kernel(const float* __restrict__ features,
                     const int*   __restrict__ neigh_idx,
                     const int*   __restrict__ nodes,
                     const int*   __restrict__ perm,
                     float*       __restrict__ out)
{
    const int slice = blockIdx.x & (SLICES - 1);    // -> XCD id (round-robin)
    const int chunk = blockIdx.x >> 3;

    const int t     = threadIdx.x;
    const int g     = t >> 3;                       // row-in-chunk 0..31
    const int lane8 = t & 7;                        // float4 column in slice

    const int b = chunk * CHUNK + g;
    const int d = slice * SLICE_D + lane8 * 4;

    // ---- skip (self) gathers first: 3-deep chain overlaps the k-loop ----
    const int n  = nodes[b];
    const int pn = perm[n];
    const f32x4 o2 = *reinterpret_cast<const f32x4*>(
        &features[(size_t)n  * D_FEAT + d]);
    const f32x4 o3 = *reinterpret_cast<const f32x4*>(
        &features[(size_t)pn * D_FEAT + d]);

    // ---- neighbor means (plain + shuffled) ----
    f32x4 acc  = {0.f, 0.f, 0.f, 0.f};
    f32x4 accs = {0.f, 0.f, 0.f, 0.f};

    #pragma unroll
    for (int k = 0; k < K_SAMPLE; ++k) {
        const int idx  = neigh_idx[b * K_SAMPLE + k];
        const int pidx = perm[idx];
        const f32x4 f  = *reinterpret_cast<const f32x4*>(
            &features[(size_t)idx  * D_FEAT + d]);
        const f32x4 fs = *reinterpret_cast<const f32x4*>(
            &features[(size_t)pidx * D_FEAT + d]);
        acc  += f;
        accs += fs;
    }

    const float inv = 1.0f / (float)K_SAMPLE;
    const f32x4 o0 = acc  * inv;
    const f32x4 o1 = accs * inv;

    // ---- stores: outputs concatenated flat in return order ----
    const size_t row = (size_t)b * D_FEAT + d;
    const size_t sec = (size_t)BATCH * D_FEAT;
    __builtin_nontemporal_store(o0, reinterpret_cast<f32x4*>(&out[row]          ));
    __builtin_nontemporal_store(o1, reinterpret_cast<f32x4*>(&out[row +     sec]));
    __builtin_nontemporal_store(o2, reinterpret_cast<f32x4*>(&out[row + 2 * sec]));
    __builtin_nontemporal_store(o3, reinterpret_cast<f32x4*>(&out[row + 3 * sec]));
}

extern "C" void kernel_launch(void* const* d_in, const int* in_sizes, int n_in,
                              void* d_out, int out_size, void* d_ws, size_t ws_size,
                              hipStream_t stream) {
    const float* features  = (const float*)d_in[0];
    const int*   neigh_idx = (const int*)  d_in[1];
    const int*   nodes     = (const int*)  d_in[2];
    const int*   perm      = (const int*)  d_in[3];
    float*       out       = (float*)d_out;

    const int grid = (BATCH / CHUNK) * SLICES;      // 512 chunks x 8 slices = 4096
    mean_agg_kernel<<<grid, THREADS, 0, stream>>>(features, neigh_idx, nodes, perm, out);
}